// Round 9
// baseline (31.311 us; speedup 1.0000x reference)
//
#include <hip/hip_runtime.h>

// GCNConv, full upper-tri graph + self loops, B=512, N=64, C=O=256.
// out[b,i,:] = relu( (1/sqrt(i+1)) * sum_{j<=i} (X[b]W)[j,:]/sqrt(j+1) + bias )
//
// R10: occupancy-for-overlap. 512 blocks x 256 thr (4 waves), 1 graph/block,
// 2 blocks/CU co-resident (LDS 32KB, VGPR<=256 via launch_bounds(256,1)).
// Per block: X loads issued first (HBM stream), W panel loads (L2) hidden
// under the X wait, convert, ONE __syncthreads (vmcnt already 0 -> no drain),
// gemm, in-register scaled prefix scan, direct stores. Cross-block phase
// stagger keeps the memory pipes continuously busy -- no intra-block
// pipelining gymnastics.

#define BATCH 512
#define NNODE 64
#define CIN   256
#define COUT  256

typedef __bf16 bf16x8 __attribute__((ext_vector_type(8)));
typedef float  f32x4  __attribute__((ext_vector_type(4)));

__global__ __launch_bounds__(256, 1) void gcn_fused(
    const float* __restrict__ X,
    const float* __restrict__ W,             // f32, [CIN][COUT] row-major
    const float* __restrict__ bias,
    float* __restrict__ out)
{
    __shared__ uint4 Xs4[2048];              // 32 KiB: swizzled bf16 X[b]
    const int tid  = threadIdx.x;
    const int lane = tid & 63;
    const int w    = tid >> 6;               // wave 0..3: cols [w*64, w*64+64)
    const int g    = lane >> 4;
    const int c    = lane & 15;
    const int b    = blockIdx.x;

    const float* xb = X + (size_t)b * (NNODE * CIN);

    // ---- 1) issue ALL X loads first (the HBM stream everything waits on) ----
    f32x4 pf[16];                            // 64 VGPR
#pragma unroll
    for (int i = 0; i < 8; ++i) {
        int ch = tid + i * 256;              // 2048 chunks of 8 floats
        const f32x4* p = reinterpret_cast<const f32x4*>(
            xb + (ch >> 5) * CIN + ((ch & 31) << 3));
        pf[2 * i]     = p[0];
        pf[2 * i + 1] = p[1];
    }

    // ---- 2) W fragments (L2-resident; issue+cvt hidden under X HBM wait) ----
    // B[k = kk*32+g*8+j][col = w*64+nt*16+c] = W[k*COUT + col]
    bf16x8 bfr[8][4];                        // 128 VGPR
    {
        const float* Wp = W + w * 64 + c;
#pragma unroll
        for (int kk = 0; kk < 8; ++kk)
#pragma unroll
            for (int nt = 0; nt < 4; ++nt) {
                bf16x8 t;
#pragma unroll
                for (int j = 0; j < 8; ++j)
                    t[j] = (__bf16)Wp[(size_t)(kk * 32 + g * 8 + j) * COUT + nt * 16];
                bfr[kk][nt] = t;
            }
    }
    float bias_c[4];
#pragma unroll
    for (int nt = 0; nt < 4; ++nt)
        bias_c[nt] = bias[w * 64 + nt * 16 + c];

    float dd[4][4];                          // 1/sqrt(row+1) table
#pragma unroll
    for (int mt = 0; mt < 4; ++mt)
#pragma unroll
        for (int r = 0; r < 4; ++r)
            dd[mt][r] = rsqrtf((float)(mt * 16 + g * 4 + r + 1));

    // ---- 3) convert X -> LDS (swizzled bf16); waits arrive per-load ----
#pragma unroll
    for (int i = 0; i < 8; ++i) {
        int ch  = tid + i * 256;
        int row = ch >> 5;
        int c8  = (ch & 31) << 3;
        f32x4 v0 = pf[2 * i], v1 = pf[2 * i + 1];
        bf16x8 h;
        h[0] = (__bf16)v0[0]; h[1] = (__bf16)v0[1];
        h[2] = (__bf16)v0[2]; h[3] = (__bf16)v0[3];
        h[4] = (__bf16)v1[0]; h[5] = (__bf16)v1[1];
        h[6] = (__bf16)v1[2]; h[7] = (__bf16)v1[3];
        int byte = (row << 9) + (c8 << 1);
        byte ^= (row & 7) << 4;
        *reinterpret_cast<uint4*>((unsigned char*)Xs4 + byte) =
            __builtin_bit_cast(uint4, h);
    }

    // vmcnt is naturally 0 here (all loads consumed) -> barrier drain is free
    __syncthreads();

    // ---- 4) GEMM: 8 kk-steps x 16 MFMA ----
    f32x4 acc[4][4] = {};                    // [mt][nt]
    const int swz = (c & 7) << 4;
#pragma unroll
    for (int kk = 0; kk < 8; ++kk) {
        bf16x8 a[4];
#pragma unroll
        for (int mt = 0; mt < 4; ++mt) {
            int byte = ((mt * 16 + c) << 9) + (kk << 6) + (g << 4);
            byte ^= swz;
            a[mt] = *reinterpret_cast<const bf16x8*>((const unsigned char*)Xs4 + byte);
        }
#pragma unroll
        for (int mt = 0; mt < 4; ++mt)
#pragma unroll
            for (int nt = 0; nt < 4; ++nt)
                acc[mt][nt] = __builtin_amdgcn_mfma_f32_16x16x32_bf16(
                    a[mt], bfr[kk][nt], acc[mt][nt], 0, 0, 0);
    }

    // ---- 5) epilogue: row-scale, prefix over 64 rows, bias+relu, store ----
    float t_[4][4];
#pragma unroll
    for (int mt = 0; mt < 4; ++mt)
#pragma unroll
        for (int nt = 0; nt < 4; ++nt) {
            f32x4 v = acc[mt][nt];
            v[0] *= dd[mt][0]; v[1] *= dd[mt][1];
            v[2] *= dd[mt][2]; v[3] *= dd[mt][3];
            v[1] += v[0]; v[2] += v[1]; v[3] += v[2];
            acc[mt][nt] = v;
            t_[mt][nt] = v[3];
        }
    // xor-butterfly exclusive scan over 4 g-groups, serial over mt
    float Ofs[4][4];                         // [mt][nt]
#pragma unroll
    for (int nt = 0; nt < 4; ++nt) {
        float run = 0.0f;
#pragma unroll
        for (int mt = 0; mt < 4; ++mt) {
            float v    = t_[mt][nt];
            float p    = __shfl_xor(v, 16, 64);
            float excl = (g & 1) ? p : 0.0f;
            float pair = v + p;
            float q    = __shfl_xor(pair, 32, 64);
            excl += (g & 2) ? q : 0.0f;
            Ofs[mt][nt] = run + excl;
            run += pair + q;
        }
    }

    float* ob = out + (size_t)b * (NNODE * COUT) + w * 64 + c;
#pragma unroll
    for (int mt = 0; mt < 4; ++mt)
#pragma unroll
        for (int r = 0; r < 4; ++r) {
            const int row = mt * 16 + g * 4 + r;
            const float dr = dd[mt][r];
#pragma unroll
            for (int nt = 0; nt < 4; ++nt) {
                float val = (acc[mt][nt][r] + Ofs[mt][nt]) * dr + bias_c[nt];
                ob[row * COUT + nt * 16] = fmaxf(val, 0.0f);
            }
        }
}

extern "C" void kernel_launch(void* const* d_in, const int* in_sizes, int n_in,
                              void* d_out, int out_size, void* d_ws, size_t ws_size,
                              hipStream_t stream) {
    const float* x = (const float*)d_in[0];
    const float* W = (const float*)d_in[1];
    const float* bsp = (const float*)d_in[2];
    float* out = (float*)d_out;

    hipLaunchKernelGGL(gcn_fused, dim3(BATCH), dim3(256), 0, stream,
                       x, W, bsp, out);
}

// Round 10
// 26.705 us; speedup vs baseline: 1.1725x; 1.1725x over previous
//
#include <hip/hip_runtime.h>

// GCNConv, full upper-tri graph + self loops, B=512, N=64, C=O=256.
// out[b,i,:] = relu( (1/sqrt(i+1)) * sum_{j<=i} (X[b]W)[j,:]/sqrt(j+1) + bias )
//
// R11: two independent barrier domains per CU. Grid 1024 = 512 graphs x 2
// col-halves, 256 thr (4 waves), launch_bounds(256,2) -> VGPR<=256 enforced,
// 2 blocks/CU co-resident (LDS 32KB each). Independent blocks phase-stagger:
// one block's HBM wait hides under the other's compute/stores. Graph-pair
// blocks mapped to the SAME XCD (bids p and p+8) so the second X read is an
// L2 hit. X staging = 1KB-contiguous wave instructions. W frags via wprep
// (bf16 [N][K] in d_ws): 16 contiguous bf16x8 loads, not 128 scalar dwords.

#define BATCH 512
#define NNODE 64
#define CIN   256
#define COUT  256

typedef __bf16 bf16x8 __attribute__((ext_vector_type(8)));
typedef __bf16 bf16x4 __attribute__((ext_vector_type(4)));
typedef float  f32x4  __attribute__((ext_vector_type(4)));

__device__ __forceinline__ unsigned int f2bf_bits(float f) {
    unsigned int u = __builtin_bit_cast(unsigned int, f);
    return (u + 0x7fffu + ((u >> 16) & 1u)) >> 16;
}

__global__ __launch_bounds__(256, 2) void gcn_fused(
    const float* __restrict__ X,
    const unsigned short* __restrict__ WT,   // bf16 bits, [COUT][CIN] (wprep)
    const float* __restrict__ bias,
    float* __restrict__ out)
{
    __shared__ uint4 Xs4[2048];              // 32 KiB: swizzled bf16 X[b]
    const int tid  = threadIdx.x;
    const int lane = tid & 63;
    const int w    = tid >> 6;               // wave 0..3
    const int g    = lane >> 4;
    const int c    = lane & 15;

    // bid -> (graph, col-half); pair (p, p+8) shares bid&7 -> same XCD.
    const int bid  = blockIdx.x;
    const int half = (bid >> 3) & 1;
    const int b    = ((bid >> 4) << 3) | (bid & 7);
    const int colbase = half * 128 + w * 32; // this wave's 32 output cols

    const float* xb = X + (size_t)b * (NNODE * CIN);

    // ---- 1) issue X loads: 16-B pieces at tid+i*256 -> each wave
    // instruction covers 1 KB contiguous (full-density segments) ----
    f32x4 pf[16];                            // 64 VGPR
#pragma unroll
    for (int i = 0; i < 16; ++i)
        pf[i] = *reinterpret_cast<const f32x4*>(xb + (size_t)(tid + i * 256) * 4);

    // ---- 2) W fragments from bf16 WT (contiguous 16B per lane, L2-hot) ----
    bf16x8 bfr[8][2];                        // 64 VGPR
    {
        const unsigned short* WTb = WT + (size_t)(colbase + c) * CIN + g * 8;
#pragma unroll
        for (int kk = 0; kk < 8; ++kk)
#pragma unroll
            for (int nt = 0; nt < 2; ++nt)
                bfr[kk][nt] = *reinterpret_cast<const bf16x8*>(WTb + nt * 16 * CIN + kk * 32);
    }
    float bias_c[2];
#pragma unroll
    for (int nt = 0; nt < 2; ++nt)
        bias_c[nt] = bias[colbase + nt * 16 + c];

    float dd[4][4];                          // 1/sqrt(row+1)
#pragma unroll
    for (int mt = 0; mt < 4; ++mt)
#pragma unroll
        for (int r = 0; r < 4; ++r)
            dd[mt][r] = rsqrtf((float)(mt * 16 + g * 4 + r + 1));

    // ---- 3) convert -> LDS (swizzled bf16); piece q = tid+i*256:
    // row = q>>6, 8-byte slot (q&63) within the 512-B bf16 row ----
#pragma unroll
    for (int i = 0; i < 16; ++i) {
        int q   = tid + i * 256;
        int row = q >> 6;
        f32x4 v = pf[i];
        bf16x4 h;
        h[0] = (__bf16)v[0]; h[1] = (__bf16)v[1];
        h[2] = (__bf16)v[2]; h[3] = (__bf16)v[3];
        int byte = (row << 9) + ((q & 63) << 3);
        byte ^= (row & 7) << 4;
        *reinterpret_cast<uint2*>((unsigned char*)Xs4 + byte) =
            __builtin_bit_cast(uint2, h);
    }

    // vmcnt naturally 0 here -> the barrier's implicit drain is free
    __syncthreads();

    // ---- 4) GEMM: 8 kk-steps x 8 MFMA ----
    f32x4 acc[4][2] = {};                    // [mt][nt]
    const int swz = (c & 7) << 4;
#pragma unroll
    for (int kk = 0; kk < 8; ++kk) {
        bf16x8 a[4];
#pragma unroll
        for (int mt = 0; mt < 4; ++mt) {
            int byte = ((mt * 16 + c) << 9) + (kk << 6) + (g << 4);
            byte ^= swz;
            a[mt] = *reinterpret_cast<const bf16x8*>((const unsigned char*)Xs4 + byte);
        }
#pragma unroll
        for (int mt = 0; mt < 4; ++mt)
#pragma unroll
            for (int nt = 0; nt < 2; ++nt)
                acc[mt][nt] = __builtin_amdgcn_mfma_f32_16x16x32_bf16(
                    a[mt], bfr[kk][nt], acc[mt][nt], 0, 0, 0);
    }

    // ---- 5) epilogue: row-scale, prefix over 64 rows, bias+relu, store ----
    float t_[4][2];
#pragma unroll
    for (int mt = 0; mt < 4; ++mt)
#pragma unroll
        for (int nt = 0; nt < 2; ++nt) {
            f32x4 v = acc[mt][nt];
            v[0] *= dd[mt][0]; v[1] *= dd[mt][1];
            v[2] *= dd[mt][2]; v[3] *= dd[mt][3];
            v[1] += v[0]; v[2] += v[1]; v[3] += v[2];
            acc[mt][nt] = v;
            t_[mt][nt] = v[3];
        }
    // xor-butterfly exclusive scan over 4 g-groups, serial over mt
    float Ofs[4][2];
#pragma unroll
    for (int nt = 0; nt < 2; ++nt) {
        float run = 0.0f;
#pragma unroll
        for (int mt = 0; mt < 4; ++mt) {
            float v    = t_[mt][nt];
            float p    = __shfl_xor(v, 16, 64);
            float excl = (g & 1) ? p : 0.0f;
            float pair = v + p;
            float q    = __shfl_xor(pair, 32, 64);
            excl += (g & 2) ? q : 0.0f;
            Ofs[mt][nt] = run + excl;
            run += pair + q;
        }
    }

    float* ob = out + (size_t)b * (NNODE * COUT) + colbase + c;
#pragma unroll
    for (int mt = 0; mt < 4; ++mt)
#pragma unroll
        for (int r = 0; r < 4; ++r) {
            const int row = mt * 16 + g * 4 + r;
            const float dr = dd[mt][r];
#pragma unroll
            for (int nt = 0; nt < 2; ++nt) {
                float val = (acc[mt][nt][r] + Ofs[mt][nt]) * dr + bias_c[nt];
                ob[row * COUT + nt * 16] = fmaxf(val, 0.0f);
            }
        }
}

// W (f32, [K=256][N=256]) -> Wt (bf16 bits, [N=256][K=256])
__global__ void wprep(const float* __restrict__ W, unsigned short* __restrict__ Wt) {
    __shared__ unsigned short tile[64][72];
    const int tid = threadIdx.x;
    const int tk  = blockIdx.x & 3;
    const int tn  = blockIdx.x >> 2;
#pragma unroll
    for (int i = 0; i < 16; ++i) {
        int idx = tid + i * 256;
        int r  = idx >> 6;
        int cc = idx & 63;
        tile[cc][r] = (unsigned short)f2bf_bits(W[(tk * 64 + r) * 256 + tn * 64 + cc]);
    }
    __syncthreads();
#pragma unroll
    for (int i = 0; i < 16; ++i) {
        int idx = tid + i * 256;
        int rr = idx >> 6;
        int cc = idx & 63;
        Wt[(tn * 64 + rr) * 256 + tk * 64 + cc] = tile[rr][cc];
    }
}

extern "C" void kernel_launch(void* const* d_in, const int* in_sizes, int n_in,
                              void* d_out, int out_size, void* d_ws, size_t ws_size,
                              hipStream_t stream) {
    const float* x = (const float*)d_in[0];
    const float* W = (const float*)d_in[1];
    const float* bsp = (const float*)d_in[2];
    float* out = (float*)d_out;
    unsigned short* Wt = (unsigned short*)d_ws;

    hipLaunchKernelGGL(wprep, dim3(16), dim3(256), 0, stream, W, Wt);
    hipLaunchKernelGGL(gcn_fused, dim3(2 * BATCH), dim3(256), 0, stream,
                       x, Wt, bsp, out);
}

// Round 11
// 24.149 us; speedup vs baseline: 1.2966x; 1.1059x over previous
//
#include <hip/hip_runtime.h>

// GCNConv, full upper-tri graph + self loops, B=512, N=64, C=O=256.
// out[b,i,:] = relu( (1/sqrt(i+1)) * sum_{j<=i} (X[b]W)[j,:]/sqrt(j+1) + bias )
//
// R12 = R8 + two fixes:
//  (1) W via wprep (bf16 [N][K]): 16 vector loads/thread instead of 128
//      scalar dwords -- un-clogs the in-order vmcnt ledger and issue slots.
//  (2) K-split staging: X staged in two 128-feature halves (16KB LDS each);
//      gemm kk=0..3 starts after half a graph arrives; later halves / next
//      graph stream under compute. lgkm-only barriers (no vmcnt drain),
//      issue order == consumption order, compiler emits counted waits.
// 256 blocks x 512 thr, 1 block/CU, 8 waves; wave w owns cols [w*32,w*32+32).

#define BATCH 512
#define NNODE 64
#define CIN   256
#define COUT  256

typedef __bf16 bf16x8 __attribute__((ext_vector_type(8)));
typedef __bf16 bf16x4 __attribute__((ext_vector_type(4)));
typedef float  f32x4  __attribute__((ext_vector_type(4)));

__device__ __forceinline__ unsigned int f2bf_bits(float f) {
    unsigned int u = __builtin_bit_cast(unsigned int, f);
    return (u + 0x7fffu + ((u >> 16) & 1u)) >> 16;
}

// barrier that waits only on LDS ops (no vmcnt drain)
#define LGKM_BARRIER() asm volatile("s_waitcnt lgkmcnt(0)\n\ts_barrier" ::: "memory")

__global__ __launch_bounds__(512, 1) void gcn_fused(
    const float* __restrict__ X,
    const unsigned short* __restrict__ WT,   // bf16 bits, [COUT][CIN] (wprep)
    const float* __restrict__ bias,
    float* __restrict__ out)
{
    __shared__ uint4 Xs4[2][1024];           // 2 x 16KB: one 128-feature half each
    const int tid  = threadIdx.x;
    const int lane = tid & 63;
    const int w    = tid >> 6;               // wave 0..7: cols [w*32, w*32+32)
    const int g    = lane >> 4;
    const int c    = lane & 15;
    const int colbase = w * 32;
    const int xg   = blockIdx.x * 2;

    const float* xb0 = X + (size_t)xg * (NNODE * CIN);
    const float* xb1 = xb0 + NNODE * CIN;

    // ---- issue order == consumption order: W(16) -> g0h0(4) -> g0h1(4) ----
    bf16x8 bfr[8][2];                        // 64 VGPR, direct vector loads
    {
        const unsigned short* WTb = WT + (size_t)(colbase + c) * CIN + g * 8;
#pragma unroll
        for (int kk = 0; kk < 8; ++kk)
#pragma unroll
            for (int nt = 0; nt < 2; ++nt)
                bfr[kk][nt] = *reinterpret_cast<const bf16x8*>(WTb + nt * 16 * CIN + kk * 32);
    }

    // staging piece q = tid + i*512 covers 4 floats of half h:
    // row = q>>5, kpos = (q&31)*4 ; global addr xb + row*CIN + h*128 + kpos
    f32x4 p00[4], p01[4];
#pragma unroll
    for (int i = 0; i < 4; ++i) {
        int q = tid + i * 512;
        p00[i] = *reinterpret_cast<const f32x4*>(xb0 + (q >> 5) * CIN + ((q & 31) << 2));
    }
#pragma unroll
    for (int i = 0; i < 4; ++i) {
        int q = tid + i * 512;
        p01[i] = *reinterpret_cast<const f32x4*>(xb0 + (q >> 5) * CIN + 128 + ((q & 31) << 2));
    }

    float bias_c[2];
#pragma unroll
    for (int nt = 0; nt < 2; ++nt)
        bias_c[nt] = bias[colbase + nt * 16 + c];
    float dd[4][4];                          // 1/sqrt(row+1)
#pragma unroll
    for (int mt = 0; mt < 4; ++mt)
#pragma unroll
        for (int r = 0; r < 4; ++r)
            dd[mt][r] = rsqrtf((float)(mt * 16 + g * 4 + r + 1));

    // cvt one staged half into LDS slot s (rows are 256B, XOR-swizzled)
    auto cvt_half = [&](f32x4 (&p)[4], int s) {
#pragma unroll
        for (int i = 0; i < 4; ++i) {
            int q   = tid + i * 512;
            int row = q >> 5;
            f32x4 v = p[i];
            bf16x4 h;
            h[0] = (__bf16)v[0]; h[1] = (__bf16)v[1];
            h[2] = (__bf16)v[2]; h[3] = (__bf16)v[3];
            int byte = (row << 8) + ((q & 31) << 3);
            byte ^= (row & 7) << 4;
            *reinterpret_cast<uint2*>((unsigned char*)Xs4[s] + byte) =
                __builtin_bit_cast(uint2, h);
        }
    };

    const int swz = (c & 7) << 4;
    // gemm over one half (4 kk steps) from LDS slot s, bfr rows [kb, kb+4)
    auto gemm_half = [&](int s, int kb, f32x4 (&acc)[4][2]) {
#pragma unroll
        for (int k2 = 0; k2 < 4; ++k2) {
            bf16x8 a[4];
#pragma unroll
            for (int mt = 0; mt < 4; ++mt) {
                int byte = ((mt * 16 + c) << 8) + (k2 << 6) + (g << 4);
                byte ^= swz;
                a[mt] = *reinterpret_cast<const bf16x8*>((const unsigned char*)Xs4[s] + byte);
            }
#pragma unroll
            for (int mt = 0; mt < 4; ++mt)
#pragma unroll
                for (int nt = 0; nt < 2; ++nt)
                    acc[mt][nt] = __builtin_amdgcn_mfma_f32_16x16x32_bf16(
                        a[mt], bfr[kb + k2][nt], acc[mt][nt], 0, 0, 0);
        }
    };

    auto epilogue = [&](f32x4 (&acc)[4][2], float* ob) {
        float t_[4][2];
#pragma unroll
        for (int mt = 0; mt < 4; ++mt)
#pragma unroll
            for (int nt = 0; nt < 2; ++nt) {
                f32x4 v = acc[mt][nt];
                v[0] *= dd[mt][0]; v[1] *= dd[mt][1];
                v[2] *= dd[mt][2]; v[3] *= dd[mt][3];
                v[1] += v[0]; v[2] += v[1]; v[3] += v[2];
                acc[mt][nt] = v;
                t_[mt][nt] = v[3];
            }
        float Ofs[4][2];
#pragma unroll
        for (int nt = 0; nt < 2; ++nt) {
            float run = 0.0f;
#pragma unroll
            for (int mt = 0; mt < 4; ++mt) {
                float v    = t_[mt][nt];
                float p    = __shfl_xor(v, 16, 64);
                float excl = (g & 1) ? p : 0.0f;
                float pair = v + p;
                float q    = __shfl_xor(pair, 32, 64);
                excl += (g & 2) ? q : 0.0f;
                Ofs[mt][nt] = run + excl;
                run += pair + q;
            }
        }
#pragma unroll
        for (int mt = 0; mt < 4; ++mt)
#pragma unroll
            for (int r = 0; r < 4; ++r) {
                const int row = mt * 16 + g * 4 + r;
                const float dr = dd[mt][r];
#pragma unroll
                for (int nt = 0; nt < 2; ++nt) {
                    float val = (acc[mt][nt][r] + Ofs[mt][nt]) * dr + bias_c[nt];
                    ob[row * COUT + nt * 16] = fmaxf(val, 0.0f);
                }
            }
    };

    // ================= pipeline =================
    cvt_half(p00, 0);                        // waits g0h0 only (g0h1 in flight)
    LGKM_BARRIER();                          // LDS[0] ready; vmem NOT drained

    f32x4 pg0[4], pg1[4];
#pragma unroll
    for (int i = 0; i < 4; ++i) {            // issue g1h0 under gemm g0h0
        int q = tid + i * 512;
        pg0[i] = *reinterpret_cast<const f32x4*>(xb1 + (q >> 5) * CIN + ((q & 31) << 2));
    }

    f32x4 acc0[4][2] = {};
    gemm_half(0, 0, acc0);                   // g0 kk 0..3
    cvt_half(p01, 1);                        // waits g0h1 (pg0 in flight)
    LGKM_BARRIER();                          // LDS[1] ready; all waves past gemm h0

#pragma unroll
    for (int i = 0; i < 4; ++i) {            // issue g1h1 under gemm g0h1
        int q = tid + i * 512;
        pg1[i] = *reinterpret_cast<const f32x4*>(xb1 + (q >> 5) * CIN + 128 + ((q & 31) << 2));
    }

    gemm_half(1, 4, acc0);                   // g0 kk 4..7
    epilogue(acc0, out + (size_t)xg * (NNODE * COUT) + colbase + c);  // stores fly

    cvt_half(pg0, 0);                        // safe: all waves past barrier 2
    LGKM_BARRIER();                          // LDS[0]=g1h0 ready; stores undrained

    f32x4 acc1[4][2] = {};
    gemm_half(0, 0, acc1);                   // g1 kk 0..3
    cvt_half(pg1, 1);                        // safe: all waves past barrier 3
    LGKM_BARRIER();

    gemm_half(1, 4, acc1);                   // g1 kk 4..7
    epilogue(acc1, out + (size_t)(xg + 1) * (NNODE * COUT) + colbase + c);
}

// W (f32, [K=256][N=256]) -> Wt (bf16 bits, [N=256][K=256])
__global__ void wprep(const float* __restrict__ W, unsigned short* __restrict__ Wt) {
    __shared__ unsigned short tile[64][72];
    const int tid = threadIdx.x;
    const int tk  = blockIdx.x & 3;
    const int tn  = blockIdx.x >> 2;
#pragma unroll
    for (int i = 0; i < 16; ++i) {
        int idx = tid + i * 256;
        int r  = idx >> 6;
        int cc = idx & 63;
        tile[cc][r] = (unsigned short)f2bf_bits(W[(tk * 64 + r) * 256 + tn * 64 + cc]);
    }
    __syncthreads();
#pragma unroll
    for (int i = 0; i < 16; ++i) {
        int idx = tid + i * 256;
        int rr = idx >> 6;
        int cc = idx & 63;
        Wt[(tn * 64 + rr) * 256 + tk * 64 + cc] = tile[rr][cc];
    }
}

extern "C" void kernel_launch(void* const* d_in, const int* in_sizes, int n_in,
                              void* d_out, int out_size, void* d_ws, size_t ws_size,
                              hipStream_t stream) {
    const float* x = (const float*)d_in[0];
    const float* W = (const float*)d_in[1];
    const float* bsp = (const float*)d_in[2];
    float* out = (float*)d_out;
    unsigned short* Wt = (unsigned short*)d_ws;

    hipLaunchKernelGGL(wprep, dim3(16), dim3(256), 0, stream, W, Wt);
    hipLaunchKernelGGL(gcn_fused, dim3(BATCH / 2), dim3(512), 0, stream,
                       x, Wt, bsp, out);
}

// Round 12
// 21.540 us; speedup vs baseline: 1.4537x; 1.1211x over previous
//
#include <hip/hip_runtime.h>

// GCNConv, full upper-tri graph + self loops, B=512, N=64, C=O=256.
// out[b,i,:] = relu( (1/sqrt(i+1)) * sum_{j<=i} (X[b]W)[j,:]/sqrt(j+1) + bias )
//
// R13 = R8 with ONLY the barrier discipline changed:
//  - both barriers are lgkm-only (s_waitcnt lgkmcnt(0); s_barrier): no vmcnt
//    drain, so g0's epilogue stores and g1's prefetch loads are never waited
//    on by a barrier.
//  - g1's X loads issued BEFORE barrier 1 (they fly under barrier + gemm g0).
//  - cvt g1 placed between gemm g0 and epilogue g0.
// Everything else (issue order, W scalar loads after X, staging layout,
// swizzle, gemm, scan, stores) is byte-identical to R8 (20.2 us anchor).

#define BATCH 512
#define NNODE 64
#define CIN   256
#define COUT  256

typedef __bf16 bf16x8 __attribute__((ext_vector_type(8)));
typedef float  f32x4  __attribute__((ext_vector_type(4)));

// barrier that waits only on LDS ops (no vmcnt drain). Proven safe in R9/R12.
#define LGKM_BARRIER() asm volatile("s_waitcnt lgkmcnt(0)\n\ts_barrier" ::: "memory")

__global__ __launch_bounds__(512, 1) void gcn_fused(
    const float* __restrict__ X,
    const float* __restrict__ W,             // f32, [CIN][COUT] row-major
    const float* __restrict__ bias,
    float* __restrict__ out)
{
    __shared__ uint4 Xs4[2][2048];           // [graph][32KB] swizzled bf16 X
    const int tid  = threadIdx.x;
    const int lane = tid & 63;
    const int w    = tid >> 6;               // wave 0..7: cols [w*32, w*32+32)
    const int g    = lane >> 4;
    const int c    = lane & 15;
    const int colbase = w * 32;
    const int xg   = blockIdx.x * 2;

    const float* xb0 = X + (size_t)xg * (NNODE * CIN);
    const float* xb1 = xb0 + NNODE * CIN;

    // ---- 1) issue g0 X loads first (the stream everything waits on) ----
    f32x4 pf[8];
#pragma unroll
    for (int i = 0; i < 4; ++i) {
        int ch  = tid + i * 512;             // 2048 chunks of 8 floats
        const f32x4* p = reinterpret_cast<const f32x4*>(
            xb0 + (ch >> 5) * CIN + ((ch & 31) << 3));
        pf[2 * i]     = p[0];
        pf[2 * i + 1] = p[1];
    }

    // ---- 2) W fragments (L2-resident; hidden under g0's HBM wait) ----
    bf16x8 bfr[8][2];                        // 64 VGPR
    {
        const float* Wp = W + colbase + c;
#pragma unroll
        for (int kk = 0; kk < 8; ++kk)
#pragma unroll
            for (int nt = 0; nt < 2; ++nt) {
                bf16x8 t;
#pragma unroll
                for (int j = 0; j < 8; ++j)
                    t[j] = (__bf16)Wp[(size_t)(kk * 32 + g * 8 + j) * COUT + nt * 16];
                bfr[kk][nt] = t;
            }
    }
    float bias_c[2];
#pragma unroll
    for (int nt = 0; nt < 2; ++nt)
        bias_c[nt] = bias[colbase + nt * 16 + c];

    // ---- 3) convert g0 -> LDS buf0 (swizzled bf16) ----
#pragma unroll
    for (int i = 0; i < 4; ++i) {
        int ch  = tid + i * 512;
        int row = ch >> 5;
        int c8  = (ch & 31) << 3;
        f32x4 v0 = pf[2 * i], v1 = pf[2 * i + 1];
        bf16x8 h;
        h[0] = (__bf16)v0[0]; h[1] = (__bf16)v0[1];
        h[2] = (__bf16)v0[2]; h[3] = (__bf16)v0[3];
        h[4] = (__bf16)v1[0]; h[5] = (__bf16)v1[1];
        h[6] = (__bf16)v1[2]; h[7] = (__bf16)v1[3];
        int byte = (row << 9) + (c8 << 1);
        byte ^= (row & 7) << 4;
        *reinterpret_cast<uint4*>((unsigned char*)Xs4[0] + byte) =
            __builtin_bit_cast(uint4, h);
    }

    // ---- 4) issue g1 X loads BEFORE barrier (no drain -> max flight time) ----
    f32x4 pg[8];
#pragma unroll
    for (int i = 0; i < 4; ++i) {
        int ch  = tid + i * 512;
        const f32x4* p = reinterpret_cast<const f32x4*>(
            xb1 + (ch >> 5) * CIN + ((ch & 31) << 3));
        pg[2 * i]     = p[0];
        pg[2 * i + 1] = p[1];
    }

    float dd[4][4];                          // 1/sqrt(row+1) table
#pragma unroll
    for (int mt = 0; mt < 4; ++mt)
#pragma unroll
        for (int r = 0; r < 4; ++r)
            dd[mt][r] = rsqrtf((float)(mt * 16 + g * 4 + r + 1));

    const int swz = (c & 7) << 4;

    auto gemm = [&](const unsigned char* Xs, f32x4 (&acc)[4][2]) {
#pragma unroll
        for (int kk = 0; kk < 8; ++kk) {
            bf16x8 a[4];
#pragma unroll
            for (int mt = 0; mt < 4; ++mt) {
                int byte = ((mt * 16 + c) << 9) + (kk << 6) + (g << 4);
                byte ^= swz;
                a[mt] = *reinterpret_cast<const bf16x8*>(Xs + byte);
            }
#pragma unroll
            for (int mt = 0; mt < 4; ++mt)
#pragma unroll
                for (int nt = 0; nt < 2; ++nt)
                    acc[mt][nt] = __builtin_amdgcn_mfma_f32_16x16x32_bf16(
                        a[mt], bfr[kk][nt], acc[mt][nt], 0, 0, 0);
        }
    };

    auto epilogue = [&](f32x4 (&acc)[4][2], float* ob) {
        float t_[4][2];
#pragma unroll
        for (int mt = 0; mt < 4; ++mt)
#pragma unroll
            for (int nt = 0; nt < 2; ++nt) {
                f32x4 v = acc[mt][nt];
                v[0] *= dd[mt][0]; v[1] *= dd[mt][1];
                v[2] *= dd[mt][2]; v[3] *= dd[mt][3];
                v[1] += v[0]; v[2] += v[1]; v[3] += v[2];
                acc[mt][nt] = v;
                t_[mt][nt] = v[3];
            }
        float Ofs[4][2];
#pragma unroll
        for (int nt = 0; nt < 2; ++nt) {
            float run = 0.0f;
#pragma unroll
            for (int mt = 0; mt < 4; ++mt) {
                float v    = t_[mt][nt];
                float p    = __shfl_xor(v, 16, 64);
                float excl = (g & 1) ? p : 0.0f;
                float pair = v + p;
                float q    = __shfl_xor(pair, 32, 64);
                excl += (g & 2) ? q : 0.0f;
                Ofs[mt][nt] = run + excl;
                run += pair + q;
            }
        }
#pragma unroll
        for (int mt = 0; mt < 4; ++mt)
#pragma unroll
            for (int r = 0; r < 4; ++r) {
                const int row = mt * 16 + g * 4 + r;
                const float dr = dd[mt][r];
#pragma unroll
                for (int nt = 0; nt < 2; ++nt) {
                    float val = (acc[mt][nt][r] + Ofs[mt][nt]) * dr + bias_c[nt];
                    ob[row * COUT + nt * 16] = fmaxf(val, 0.0f);
                }
            }
    };

    // ---- barrier 1: LDS-only wait; g1's loads stay in flight ----
    LGKM_BARRIER();

    f32x4 acc0[4][2] = {};
    gemm((const unsigned char*)Xs4[0], acc0);

    // ---- convert g1 -> LDS buf1 (pg arrived under gemm g0; LDS1 is
    // first-touched and all waves passed barrier 1 -> race-free) ----
#pragma unroll
    for (int i = 0; i < 4; ++i) {
        int ch  = tid + i * 512;
        int row = ch >> 5;
        int c8  = (ch & 31) << 3;
        f32x4 v0 = pg[2 * i], v1 = pg[2 * i + 1];
        bf16x8 h;
        h[0] = (__bf16)v0[0]; h[1] = (__bf16)v0[1];
        h[2] = (__bf16)v0[2]; h[3] = (__bf16)v0[3];
        h[4] = (__bf16)v1[0]; h[5] = (__bf16)v1[1];
        h[6] = (__bf16)v1[2]; h[7] = (__bf16)v1[3];
        int byte = (row << 9) + (c8 << 1);
        byte ^= (row & 7) << 4;
        *reinterpret_cast<uint4*>((unsigned char*)Xs4[1] + byte) =
            __builtin_bit_cast(uint4, h);
    }

    // ---- g0 epilogue: stores fly, never drained by a barrier ----
    epilogue(acc0, out + (size_t)xg * (NNODE * COUT) + colbase + c);

    // ---- barrier 2: LDS-only wait (g0 stores keep draining underneath) ----
    LGKM_BARRIER();

    f32x4 acc1[4][2] = {};
    gemm((const unsigned char*)Xs4[1], acc1);
    epilogue(acc1, out + (size_t)(xg + 1) * (NNODE * COUT) + colbase + c);
}

extern "C" void kernel_launch(void* const* d_in, const int* in_sizes, int n_in,
                              void* d_out, int out_size, void* d_ws, size_t ws_size,
                              hipStream_t stream) {
    const float* x = (const float*)d_in[0];
    const float* W = (const float*)d_in[1];
    const float* bsp = (const float*)d_in[2];
    float* out = (float*)d_out;

    hipLaunchKernelGGL(gcn_fused, dim3(BATCH / 2), dim3(512), 0, stream,
                       x, W, bsp, out);
}